// Round 1
// baseline (290.802 us; speedup 1.0000x reference)
//
#include <hip/hip_runtime.h>

// EMA via chunked linear scan.
//   y_t = a*y_{t-1} + w*x_t,  a = 1-w (per-channel constant), y_{-1} = initial_state
// K1: per chunk (length L), compute local scan final value with zero seed.
// K2: per (b,c), sequentially combine chunk carries: s_{p+1} = a^L * s_p + last_p.
// K3: per chunk, rerun recurrence seeded with carry-in, write all outputs.

#define CHUNK_L 64  // power of two; T % CHUNK_L == 0

__device__ __forceinline__ float clip01(float v) {
    return fminf(fmaxf(v, 0.0f), 1.0f);
}

__global__ __launch_bounds__(64) void ema_k1_chunk_last(
    const float* __restrict__ x, const float* __restrict__ smooth,
    float* __restrict__ chunk_last, int T, int C, int P) {
    const int blk = blockIdx.x;          // b*P + p
    const int b = blk / P;
    const int p = blk - b * P;
    const int c = threadIdx.x << 2;      // 4 channels per thread

    float4 w4 = *(const float4*)(smooth + c);
    w4.x = clip01(w4.x); w4.y = clip01(w4.y); w4.z = clip01(w4.z); w4.w = clip01(w4.w);
    const float ax = 1.0f - w4.x, ay = 1.0f - w4.y, az = 1.0f - w4.z, aw = 1.0f - w4.w;

    const int sF4 = C >> 2;              // float4 stride between consecutive t
    const float4* xp = (const float4*)(x + ((size_t)b * T + (size_t)p * CHUNK_L) * C) + (c >> 2);

    float y0 = 0.0f, y1 = 0.0f, y2 = 0.0f, y3 = 0.0f;
#pragma unroll 8
    for (int i = 0; i < CHUNK_L; ++i) {
        float4 xv = xp[(size_t)i * sF4];
        y0 = fmaf(ax, y0, w4.x * xv.x);
        y1 = fmaf(ay, y1, w4.y * xv.y);
        y2 = fmaf(az, y2, w4.z * xv.z);
        y3 = fmaf(aw, y3, w4.w * xv.w);
    }
    float4 r; r.x = y0; r.y = y1; r.z = y2; r.w = y3;
    *(float4*)(chunk_last + (size_t)blk * C + c) = r;
}

__global__ void ema_k2_carry_scan(
    const float* __restrict__ chunk_last, const float* __restrict__ init,
    const float* __restrict__ smooth, float* __restrict__ carry_in,
    int C, int P) {
    const int b = blockIdx.x;
    const int c = threadIdx.x;
    const float w = clip01(smooth[c]);
    const float a = 1.0f - w;
    float aL = a;                         // a^CHUNK_L by repeated squaring
    for (int e = CHUNK_L; e > 1; e >>= 1) aL *= aL;

    float s = init[(size_t)b * C + c];
    for (int p = 0; p < P; ++p) {
        const size_t idx = ((size_t)b * P + p) * C + c;
        carry_in[idx] = s;
        s = fmaf(aL, s, chunk_last[idx]);
    }
}

__global__ __launch_bounds__(64) void ema_k3_apply(
    const float* __restrict__ x, const float* __restrict__ smooth,
    const float* __restrict__ carry_in, float* __restrict__ out,
    int T, int C, int P) {
    const int blk = blockIdx.x;          // b*P + p
    const int b = blk / P;
    const int p = blk - b * P;
    const int c = threadIdx.x << 2;

    float4 w4 = *(const float4*)(smooth + c);
    w4.x = clip01(w4.x); w4.y = clip01(w4.y); w4.z = clip01(w4.z); w4.w = clip01(w4.w);
    const float ax = 1.0f - w4.x, ay = 1.0f - w4.y, az = 1.0f - w4.z, aw = 1.0f - w4.w;

    const float4 s4 = *(const float4*)(carry_in + (size_t)blk * C + c);
    float y0 = s4.x, y1 = s4.y, y2 = s4.z, y3 = s4.w;

    const int sF4 = C >> 2;
    const size_t base = ((size_t)b * T + (size_t)p * CHUNK_L) * C;
    const float4* xp = (const float4*)(x + base) + (c >> 2);
    float4* op = (float4*)(out + base) + (c >> 2);

#pragma unroll 8
    for (int i = 0; i < CHUNK_L; ++i) {
        float4 xv = xp[(size_t)i * sF4];
        y0 = fmaf(ax, y0, w4.x * xv.x);
        y1 = fmaf(ay, y1, w4.y * xv.y);
        y2 = fmaf(az, y2, w4.z * xv.z);
        y3 = fmaf(aw, y3, w4.w * xv.w);
        float4 r; r.x = y0; r.y = y1; r.z = y2; r.w = y3;
        op[(size_t)i * sF4] = r;
    }
}

extern "C" void kernel_launch(void* const* d_in, const int* in_sizes, int n_in,
                              void* d_out, int out_size, void* d_ws, size_t ws_size,
                              hipStream_t stream) {
    const float* x      = (const float*)d_in[0];  // [B, T, C]
    const float* init   = (const float*)d_in[1];  // [B, C]
    const float* smooth = (const float*)d_in[2];  // [C]
    float* out = (float*)d_out;

    const int C  = in_sizes[2];
    const int BC = in_sizes[1];
    const int B  = BC / C;
    const int T  = in_sizes[0] / BC;
    const int P  = T / CHUNK_L;

    float* ws1 = (float*)d_ws;                    // chunk_last [B, P, C]
    float* ws2 = ws1 + (size_t)B * P * C;         // carry_in   [B, P, C]

    ema_k1_chunk_last<<<dim3(B * P), dim3(C / 4), 0, stream>>>(x, smooth, ws1, T, C, P);
    ema_k2_carry_scan<<<dim3(B), dim3(C), 0, stream>>>(ws1, init, smooth, ws2, C, P);
    ema_k3_apply<<<dim3(B * P), dim3(C / 4), 0, stream>>>(x, smooth, ws2, out, T, C, P);
}

// Round 2
// 271.194 us; speedup vs baseline: 1.0723x; 1.0723x over previous
//
#include <hip/hip_runtime.h>

// EMA y_t = w*x_t + (1-w)*y_{t-1}, a = 1-w per-channel constant.
// 2-kernel chunked scan, chunk length L=64, P = T/L = 128 chunks per batch row.
//
// K1: per (b,p) block, local scan with zero seed -> chunk_last[b,p,:]  (2 MB ws)
// K2: per (b,p) block, recompute carry-in by scanning chunk_last[b,0..p-1,:]
//     (L2/L3-resident, ~4 us aggregate redundant work), then re-stream the
//     chunk (x is L3-warm from K1) and write outputs.
//
// Streaming loops use manual batch-of-8 float4 loads so each wave keeps 8 KB
// in flight regardless of how the compiler schedules a runtime-strided loop.

#define CHUNK_L 64

__device__ __forceinline__ float clip01(float v) {
    return fminf(fmaxf(v, 0.0f), 1.0f);
}

__global__ __launch_bounds__(64) void ema_k1_chunk_last(
    const float* __restrict__ x, const float* __restrict__ smooth,
    float* __restrict__ chunk_last, int T, int C, int P) {
    const int blk = blockIdx.x;          // b*P + p
    const int b = blk / P;
    const int p = blk - b * P;
    const int c = threadIdx.x << 2;

    float4 w4 = *(const float4*)(smooth + c);
    w4.x = clip01(w4.x); w4.y = clip01(w4.y); w4.z = clip01(w4.z); w4.w = clip01(w4.w);
    const float ax = 1.0f - w4.x, ay = 1.0f - w4.y, az = 1.0f - w4.z, aw = 1.0f - w4.w;

    const int sF4 = C >> 2;
    const float4* xp = (const float4*)(x + ((size_t)b * T + (size_t)p * CHUNK_L) * C) + threadIdx.x;

    float y0 = 0.0f, y1 = 0.0f, y2 = 0.0f, y3 = 0.0f;
    for (int i0 = 0; i0 < CHUNK_L; i0 += 8) {
        float4 xv[8];
#pragma unroll
        for (int j = 0; j < 8; ++j) xv[j] = xp[(size_t)(i0 + j) * sF4];
#pragma unroll
        for (int j = 0; j < 8; ++j) {
            y0 = fmaf(ax, y0, w4.x * xv[j].x);
            y1 = fmaf(ay, y1, w4.y * xv[j].y);
            y2 = fmaf(az, y2, w4.z * xv[j].z);
            y3 = fmaf(aw, y3, w4.w * xv[j].w);
        }
    }
    float4 r; r.x = y0; r.y = y1; r.z = y2; r.w = y3;
    *(float4*)(chunk_last + (size_t)blk * C + c) = r;
}

__global__ __launch_bounds__(64) void ema_k2_apply(
    const float* __restrict__ x, const float* __restrict__ smooth,
    const float* __restrict__ chunk_last, const float* __restrict__ init,
    float* __restrict__ out, int T, int C, int P) {
    const int blk = blockIdx.x;          // b*P + p
    const int b = blk / P;
    const int p = blk - b * P;
    const int c = threadIdx.x << 2;

    float4 w4 = *(const float4*)(smooth + c);
    w4.x = clip01(w4.x); w4.y = clip01(w4.y); w4.z = clip01(w4.z); w4.w = clip01(w4.w);
    const float ax = 1.0f - w4.x, ay = 1.0f - w4.y, az = 1.0f - w4.z, aw = 1.0f - w4.w;

    // aL = a^CHUNK_L by repeated squaring (6 squarings for L=64)
    float aLx = ax, aLy = ay, aLz = az, aLw = aw;
    for (int e = CHUNK_L; e > 1; e >>= 1) { aLx *= aLx; aLy *= aLy; aLz *= aLz; aLw *= aLw; }

    // carry-in: scan chunk_last[b, 0..p-1, c] seeded with init (L2/L3 reads)
    float4 s = *(const float4*)(init + (size_t)b * C + c);
    const float* cl = chunk_last + (size_t)b * P * C + c;
    int q = 0;
    for (; q + 8 <= p; q += 8) {
        float4 l[8];
#pragma unroll
        for (int j = 0; j < 8; ++j) l[j] = *(const float4*)(cl + (size_t)(q + j) * C);
#pragma unroll
        for (int j = 0; j < 8; ++j) {
            s.x = fmaf(aLx, s.x, l[j].x);
            s.y = fmaf(aLy, s.y, l[j].y);
            s.z = fmaf(aLz, s.z, l[j].z);
            s.w = fmaf(aLw, s.w, l[j].w);
        }
    }
    for (; q < p; ++q) {
        float4 l = *(const float4*)(cl + (size_t)q * C);
        s.x = fmaf(aLx, s.x, l.x);
        s.y = fmaf(aLy, s.y, l.y);
        s.z = fmaf(aLz, s.z, l.z);
        s.w = fmaf(aLw, s.w, l.w);
    }

    // apply: re-stream this chunk seeded with s (x L3-warm), write out
    const int sF4 = C >> 2;
    const size_t base = ((size_t)b * T + (size_t)p * CHUNK_L) * C;
    const float4* xp = (const float4*)(x + base) + threadIdx.x;
    float4* op = (float4*)(out + base) + threadIdx.x;

    float y0 = s.x, y1 = s.y, y2 = s.z, y3 = s.w;
    for (int i0 = 0; i0 < CHUNK_L; i0 += 8) {
        float4 xv[8];
#pragma unroll
        for (int j = 0; j < 8; ++j) xv[j] = xp[(size_t)(i0 + j) * sF4];
#pragma unroll
        for (int j = 0; j < 8; ++j) {
            y0 = fmaf(ax, y0, w4.x * xv[j].x);
            y1 = fmaf(ay, y1, w4.y * xv[j].y);
            y2 = fmaf(az, y2, w4.z * xv[j].z);
            y3 = fmaf(aw, y3, w4.w * xv[j].w);
            float4 r; r.x = y0; r.y = y1; r.z = y2; r.w = y3;
            op[(size_t)(i0 + j) * sF4] = r;
        }
    }
}

extern "C" void kernel_launch(void* const* d_in, const int* in_sizes, int n_in,
                              void* d_out, int out_size, void* d_ws, size_t ws_size,
                              hipStream_t stream) {
    const float* x      = (const float*)d_in[0];  // [B, T, C]
    const float* init   = (const float*)d_in[1];  // [B, C]
    const float* smooth = (const float*)d_in[2];  // [C]
    float* out = (float*)d_out;

    const int C  = in_sizes[2];
    const int BC = in_sizes[1];
    const int B  = BC / C;
    const int T  = in_sizes[0] / BC;
    const int P  = T / CHUNK_L;

    float* chunk_last = (float*)d_ws;             // [B, P, C]

    ema_k1_chunk_last<<<dim3(B * P), dim3(C / 4), 0, stream>>>(x, smooth, chunk_last, T, C, P);
    ema_k2_apply<<<dim3(B * P), dim3(C / 4), 0, stream>>>(x, smooth, chunk_last, init, out, T, C, P);
}